// Round 1
// baseline (562.750 us; speedup 1.0000x reference)
//
#include <hip/hip_runtime.h>

// Row-wise L2-clip + noise:  out[r,:] = x[r,:] / max(||x[r,:]||_2, 1) + noise[r,:]
// (L2_NORM_CLIP = 1.0, noise multiplier already folded into the noise input.)
//
// Layout: D = 128 floats/row. One 32-lane half-wave per row, float4 per lane
// (16 B/lane coalescing sweet spot). 5-step shfl_xor reduction (offsets < 32
// stay inside the half-wave on wave64). Memory-bound: 768 MB total traffic.

constexpr int D = 128;

__global__ __launch_bounds__(256) void dp_clip_noise_kernel(
    const float* __restrict__ x,
    const float* __restrict__ noise,
    float* __restrict__ out,
    int n_rows)
{
    const int tid    = blockIdx.x * blockDim.x + threadIdx.x;
    const int row    = tid >> 5;          // 32 lanes per row
    const int lane32 = tid & 31;
    if (row >= n_rows) return;

    const long long base = (long long)row * D + lane32 * 4;

    const float4 x4 = *reinterpret_cast<const float4*>(x + base);

    // per-lane partial sum of squares
    float s = x4.x * x4.x + x4.y * x4.y + x4.z * x4.z + x4.w * x4.w;

    // reduce across the 32 lanes covering this row (xor offsets < 32 keep
    // traffic within the half-wave on a 64-lane wavefront)
    s += __shfl_xor(s, 16, 64);
    s += __shfl_xor(s,  8, 64);
    s += __shfl_xor(s,  4, 64);
    s += __shfl_xor(s,  2, 64);
    s += __shfl_xor(s,  1, 64);

    const float norm  = sqrtf(s);
    const float scale = (norm > 1.0f) ? (1.0f / norm) : 1.0f;

    const float4 n4 = *reinterpret_cast<const float4*>(noise + base);

    float4 o4;
    o4.x = fmaf(x4.x, scale, n4.x);
    o4.y = fmaf(x4.y, scale, n4.y);
    o4.z = fmaf(x4.z, scale, n4.z);
    o4.w = fmaf(x4.w, scale, n4.w);

    *reinterpret_cast<float4*>(out + base) = o4;
}

extern "C" void kernel_launch(void* const* d_in, const int* in_sizes, int n_in,
                              void* d_out, int out_size, void* d_ws, size_t ws_size,
                              hipStream_t stream)
{
    const float* x     = (const float*)d_in[0];
    const float* noise = (const float*)d_in[1];
    float*       out   = (float*)d_out;

    const int n_rows = in_sizes[0] / D;          // 524288

    // 32 threads per row, 256 threads per block -> 8 rows/block
    const int total_threads = n_rows * 32;
    const int block = 256;
    const int grid  = (total_threads + block - 1) / block;

    dp_clip_noise_kernel<<<grid, block, 0, stream>>>(x, noise, out, n_rows);
}